// Round 1
// baseline (834.760 us; speedup 1.0000x reference)
//
#include <hip/hip_runtime.h>

// Problem constants (fp32 RQ-VAE nearest-codebook step)
#define Bn 8192
#define Kn 8192
#define Dn 512
#define KSPLIT 16          // K-dimension split across blocks for occupancy
#define BM 128             // row tile (x rows)
#define BN 128             // col tile (codebook entries)
#define BD 16              // contraction chunk staged in LDS
#define LDSW 132           // 128 + 4 pad: keeps 16B alignment, breaks bank strides

// Order-preserving map float -> u32 (monotone under unsigned compare, finite inputs)
__device__ __forceinline__ unsigned int fkey(float f) {
    unsigned int u = __float_as_uint(f);
    return (u & 0x80000000u) ? ~u : (u | 0x80000000u);
}

// ---------------- kernel 1: e_sq[k] = ||E[k]||^2 ----------------
__global__ __launch_bounds__(256) void esq_kernel(const float* __restrict__ E,
                                                  float* __restrict__ esq) {
    int wave = threadIdx.x >> 6;          // 4 waves/block, one row each
    int lane = threadIdx.x & 63;
    int k = blockIdx.x * 4 + wave;
    const float4* row = (const float4*)(E + (size_t)k * Dn);
    float4 v0 = row[lane];                // 512 floats = 128 float4 = 2 per lane
    float4 v1 = row[64 + lane];
    float s = v0.x*v0.x + v0.y*v0.y + v0.z*v0.z + v0.w*v0.w
            + v1.x*v1.x + v1.y*v1.y + v1.z*v1.z + v1.w*v1.w;
    #pragma unroll
    for (int off = 32; off > 0; off >>= 1) s += __shfl_down(s, off, 64);
    if (lane == 0) esq[k] = s;
}

// ---------------- kernel 2: tiled cross-term + running argmin ----------------
// dist(b,k) = e_sq[k] - 2 * <x_b, e_k>   (x_sq dropped: constant per row)
__global__ __launch_bounds__(256, 2) void argmin_kernel(
    const float* __restrict__ X, const float* __restrict__ E,
    const float* __restrict__ esq, unsigned long long* __restrict__ best)
{
    __shared__ __align__(16) float Xs[BD][LDSW];   // [d][m], transposed stage
    __shared__ __align__(16) float Es[BD][LDSW];   // [d][n]
    __shared__ unsigned long long red[BM][16];     // final cross-thread reduce

    const int tid = threadIdx.x;
    const int tx = tid & 15;              // 16 x 16 thread grid, 8x8 microtile
    const int ty = tid >> 4;
    const int rowTile = blockIdx.x / KSPLIT;
    const int split   = blockIdx.x % KSPLIT;
    const int m0 = rowTile * BM;
    const int kbase = split * (Kn / KSPLIT);   // 512-wide K range per block

    float bestv[8];
    int   besti[8];
    #pragma unroll
    for (int i = 0; i < 8; ++i) { bestv[i] = INFINITY; besti[i] = 0; }

    const int ldRow = tid >> 2;           // 0..63 (each thread loads 2 rows)
    const int ldD   = (tid & 3) * 4;      // 0,4,8,12

    for (int kt = 0; kt < (Kn / KSPLIT) / BN; ++kt) {   // 4 k-tiles
        const int k0 = kbase + kt * BN;
        float acc[8][8] = {};             // cross products, fp32

        for (int dc = 0; dc < Dn / BD; ++dc) {          // 32 d-chunks
            const int d0 = dc * BD;
            // global loads issued before barrier for latency overlap
            float4 xa = *(const float4*)&X[(size_t)(m0 + ldRow)      * Dn + d0 + ldD];
            float4 xb = *(const float4*)&X[(size_t)(m0 + 64 + ldRow) * Dn + d0 + ldD];
            float4 ea = *(const float4*)&E[(size_t)(k0 + ldRow)      * Dn + d0 + ldD];
            float4 eb = *(const float4*)&E[(size_t)(k0 + 64 + ldRow) * Dn + d0 + ldD];
            __syncthreads();   // previous chunk's LDS reads done before overwrite
            Xs[ldD+0][ldRow] = xa.x; Xs[ldD+1][ldRow] = xa.y;
            Xs[ldD+2][ldRow] = xa.z; Xs[ldD+3][ldRow] = xa.w;
            Xs[ldD+0][64+ldRow] = xb.x; Xs[ldD+1][64+ldRow] = xb.y;
            Xs[ldD+2][64+ldRow] = xb.z; Xs[ldD+3][64+ldRow] = xb.w;
            Es[ldD+0][ldRow] = ea.x; Es[ldD+1][ldRow] = ea.y;
            Es[ldD+2][ldRow] = ea.z; Es[ldD+3][ldRow] = ea.w;
            Es[ldD+0][64+ldRow] = eb.x; Es[ldD+1][64+ldRow] = eb.y;
            Es[ldD+2][64+ldRow] = eb.z; Es[ldD+3][64+ldRow] = eb.w;
            __syncthreads();

            #pragma unroll
            for (int d = 0; d < BD; ++d) {
                float a8[8], b8[8];
                // split 4+4 microtile: offsets 4*tx / 64+4*tx -> 2-way LDS (free)
                *(float4*)&a8[0] = *(const float4*)&Xs[d][4*ty];
                *(float4*)&a8[4] = *(const float4*)&Xs[d][64 + 4*ty];
                *(float4*)&b8[0] = *(const float4*)&Es[d][4*tx];
                *(float4*)&b8[4] = *(const float4*)&Es[d][64 + 4*tx];
                #pragma unroll
                for (int i = 0; i < 8; ++i)
                    #pragma unroll
                    for (int j = 0; j < 8; ++j)
                        acc[i][j] += a8[i] * b8[j];
            }
        }

        // fold this k-tile into the per-thread running argmin
        // column order ascending in j => strict '<' keeps lowest index on ties
        #pragma unroll
        for (int j = 0; j < 8; ++j) {
            const int c = k0 + ((j < 4) ? (4*tx + j) : (64 + 4*tx + (j - 4)));
            const float eq = esq[c];
            #pragma unroll
            for (int i = 0; i < 8; ++i) {
                float dval = eq - 2.0f * acc[i][j];
                if (dval < bestv[i]) { bestv[i] = dval; besti[i] = c; }
            }
        }
    }

    // cross-thread (tx) reduce per row via LDS, packed u64 keeps lowest idx on ties
    #pragma unroll
    for (int i = 0; i < 8; ++i) {
        int rloc = (i < 4) ? (4*ty + i) : (64 + 4*ty + (i - 4));
        red[rloc][tx] = ((unsigned long long)fkey(bestv[i]) << 32) |
                        (unsigned long long)(unsigned int)besti[i];
    }
    __syncthreads();
    if (tid < BM) {
        unsigned long long m = red[tid][0];
        #pragma unroll
        for (int t = 1; t < 16; ++t) {
            unsigned long long v = red[tid][t];
            if (v < m) m = v;
        }
        best[(size_t)(m0 + tid) * KSPLIT + split] = m;
    }
}

// ---------------- kernel 3: reduce splits, write index + residual ----------------
__global__ __launch_bounds__(128) void finalize_kernel(
    const float* __restrict__ X, const float* __restrict__ E,
    const unsigned long long* __restrict__ best, float* __restrict__ out)
{
    __shared__ int sidx;
    const int b = blockIdx.x;
    if (threadIdx.x == 0) {
        const unsigned long long* p = best + (size_t)b * KSPLIT;
        unsigned long long m = p[0];
        #pragma unroll
        for (int t = 1; t < KSPLIT; ++t) {
            unsigned long long v = p[t];
            if (v < m) m = v;
        }
        int idx = (int)(unsigned int)(m & 0xFFFFFFFFull);
        sidx = idx;
        out[b] = (float)idx;      // index output, read back as fp32
    }
    __syncthreads();
    const int idx = sidx;
    const float4* xr = (const float4*)(X + (size_t)b * Dn);
    const float4* er = (const float4*)(E + (size_t)idx * Dn);
    float4 x = xr[threadIdx.x];
    float4 e = er[threadIdx.x];
    float4 r; r.x = x.x - e.x; r.y = x.y - e.y; r.z = x.z - e.z; r.w = x.w - e.w;
    ((float4*)(out + Bn + (size_t)b * Dn))[threadIdx.x] = r;
}

extern "C" void kernel_launch(void* const* d_in, const int* in_sizes, int n_in,
                              void* d_out, int out_size, void* d_ws, size_t ws_size,
                              hipStream_t stream) {
    const float* X = (const float*)d_in[0];   // previous_residual [B, D]
    const float* E = (const float*)d_in[1];   // codebook_embeddings [K, D]
    float* out = (float*)d_out;               // [B] idx-as-float ++ [B*D] residual

    // workspace layout: e_sq (K floats = 32KB) | best (B*KSPLIT u64 = 1MB)
    float* esq = (float*)d_ws;
    unsigned long long* best =
        (unsigned long long*)((char*)d_ws + (size_t)Kn * sizeof(float));

    esq_kernel<<<Kn / 4, 256, 0, stream>>>(E, esq);
    argmin_kernel<<<(Bn / BM) * KSPLIT, 256, 0, stream>>>(X, E, esq, best);
    finalize_kernel<<<Bn, 128, 0, stream>>>(X, E, best, out);
}

// Round 2
// 288.861 us; speedup vs baseline: 2.8898x; 2.8898x over previous
//
#include <hip/hip_runtime.h>

// Problem constants (fp32 RQ-VAE nearest-codebook step)
#define Bn 8192
#define Kn 8192
#define Dn 512

typedef _Float16 half8 __attribute__((ext_vector_type(8)));
typedef _Float16 half4_t __attribute__((ext_vector_type(4)));
typedef float floatx4 __attribute__((ext_vector_type(4)));
typedef unsigned long long u64;

// Order-preserving map float -> u32 (monotone under unsigned compare, finite inputs)
__device__ __forceinline__ unsigned int fkey(float f) {
    unsigned int u = __float_as_uint(f);
    return (u & 0x80000000u) ? ~u : (u | 0x80000000u);
}

// async global->LDS, 16B per lane (global_load_lds_dwordx4)
__device__ __forceinline__ void gld16(const _Float16* g, _Float16* l) {
    const unsigned int* gu = (const unsigned int*)g;
    unsigned int* lu = (unsigned int*)l;
    __builtin_amdgcn_global_load_lds(
        (const __attribute__((address_space(1))) unsigned int*)gu,
        (__attribute__((address_space(3))) unsigned int*)lu, 16, 0, 0);
}

// ---------------- kernel: e_sq[k] = ||E[k]||^2 (fp32, exact path) ----------------
__global__ __launch_bounds__(256) void esq_kernel(const float* __restrict__ E,
                                                  float* __restrict__ esq) {
    int wave = threadIdx.x >> 6;
    int lane = threadIdx.x & 63;
    int k = blockIdx.x * 4 + wave;
    const float4* row = (const float4*)(E + (size_t)k * Dn);
    float4 v0 = row[lane];
    float4 v1 = row[64 + lane];
    float s = v0.x*v0.x + v0.y*v0.y + v0.z*v0.z + v0.w*v0.w
            + v1.x*v1.x + v1.y*v1.y + v1.z*v1.z + v1.w*v1.w;
    #pragma unroll
    for (int off = 32; off > 0; off >>= 1) s += __shfl_down(s, off, 64);
    if (lane == 0) esq[k] = s;
}

// ---------------- kernel: fp32 -> (hi, lo) fp16 Dekker split ----------------
// blocks [0,4096) convert X, [4096,8192) convert E; 4 elems/thread.
__global__ __launch_bounds__(256) void convert_kernel(
    const float* __restrict__ X, const float* __restrict__ E,
    _Float16* __restrict__ Xh, _Float16* __restrict__ Xl,
    _Float16* __restrict__ Eh, _Float16* __restrict__ El)
{
    const bool isE = blockIdx.x >= 4096;
    const size_t base = ((size_t)(blockIdx.x & 4095) * 256 + threadIdx.x) * 4;
    const float4 v = *(const float4*)((isE ? E : X) + base);
    half4_t h, l;
    h[0] = (_Float16)v.x; l[0] = (_Float16)(v.x - (float)h[0]);
    h[1] = (_Float16)v.y; l[1] = (_Float16)(v.y - (float)h[1]);
    h[2] = (_Float16)v.z; l[2] = (_Float16)(v.z - (float)h[2]);
    h[3] = (_Float16)v.w; l[3] = (_Float16)(v.w - (float)h[3]);
    *(half4_t*)((isE ? Eh : Xh) + base) = h;
    *(half4_t*)((isE ? El : Xl) + base) = l;
}

// ---------------- kernel: MFMA cross-term + fused argmin ----------------
// dist(b,k) = e_sq[k] - 2*(xh.eh + xh.el + xl.eh);  128x128 block tile,
// 4 waves of 64x64 (4x4 of 16x16x32 f16 MFMA), global_load_lds staging.
__global__ __launch_bounds__(256, 3) void argmin_mfma(
    const _Float16* __restrict__ Xh, const _Float16* __restrict__ Xl,
    const _Float16* __restrict__ Eh, const _Float16* __restrict__ El,
    const float* __restrict__ esq, u64* __restrict__ best)
{
    __shared__ __align__(16) _Float16 sXh[128 * 32];
    __shared__ __align__(16) _Float16 sXl[128 * 32];
    __shared__ __align__(16) _Float16 sEh[128 * 32];
    __shared__ __align__(16) _Float16 sEl[128 * 32];
    __shared__ u64 red[128][2];

    const int tid  = threadIdx.x;
    const int mb   = blockIdx.x >> 6;      // 64 m-blocks
    const int nb   = blockIdx.x & 63;      // 64 n-blocks
    const int m0   = mb * 128, n0 = nb * 128;
    const int lane = tid & 63, wave = tid >> 6;
    const int wx   = wave & 1, wy = wave >> 1;   // wave tile origin (wy*64, wx*64)
    const int colg = lane & 15, quad = lane >> 4;

    floatx4 acc[4][4];
    #pragma unroll
    for (int i = 0; i < 4; ++i)
        #pragma unroll
        for (int j = 0; j < 4; ++j) acc[i][j] = {0.f, 0.f, 0.f, 0.f};

    // staging map: thread t -> tile element t*8 (row t/4, k-quarter t%4)
    const int trow = tid >> 2;
    const int tcol = (tid & 3) * 8;
    const _Float16* gXh = Xh + (size_t)(m0 + trow) * Dn + tcol;
    const _Float16* gXl = Xl + (size_t)(m0 + trow) * Dn + tcol;
    const _Float16* gEh = Eh + (size_t)(n0 + trow) * Dn + tcol;
    const _Float16* gEl = El + (size_t)(n0 + trow) * Dn + tcol;
    const size_t rstep = (size_t)64 * Dn;   // second 64-row half
    _Float16* sXh0 = &sXh[tid * 8]; _Float16* sXl0 = &sXl[tid * 8];
    _Float16* sEh0 = &sEh[tid * 8]; _Float16* sEl0 = &sEl[tid * 8];

    const int abase = (wy * 64 + colg) * 32 + quad * 8;
    const int bbase = (wx * 64 + colg) * 32 + quad * 8;

    for (int d0 = 0; d0 < Dn; d0 += 32) {
        __syncthreads();                       // prev chunk's LDS reads done
        gld16(gXh + d0,         sXh0);
        gld16(gXh + rstep + d0, sXh0 + 2048);
        gld16(gXl + d0,         sXl0);
        gld16(gXl + rstep + d0, sXl0 + 2048);
        gld16(gEh + d0,         sEh0);
        gld16(gEh + rstep + d0, sEh0 + 2048);
        gld16(gEl + d0,         sEl0);
        gld16(gEl + rstep + d0, sEl0 + 2048);
        __syncthreads();                       // drains vmcnt -> data visible

        half8 bh[4], bl[4];
        #pragma unroll
        for (int ni = 0; ni < 4; ++ni) {
            bh[ni] = *(const half8*)&sEh[bbase + ni * 16 * 32];
            bl[ni] = *(const half8*)&sEl[bbase + ni * 16 * 32];
        }
        #pragma unroll
        for (int mi = 0; mi < 4; ++mi) {
            half8 ah = *(const half8*)&sXh[abase + mi * 16 * 32];
            half8 al = *(const half8*)&sXl[abase + mi * 16 * 32];
            #pragma unroll
            for (int ni = 0; ni < 4; ++ni) {
                acc[mi][ni] = __builtin_amdgcn_mfma_f32_16x16x32_f16(ah, bh[ni], acc[mi][ni], 0, 0, 0);
                acc[mi][ni] = __builtin_amdgcn_mfma_f32_16x16x32_f16(ah, bl[ni], acc[mi][ni], 0, 0, 0);
                acc[mi][ni] = __builtin_amdgcn_mfma_f32_16x16x32_f16(al, bh[ni], acc[mi][ni], 0, 0, 0);
            }
        }
    }

    // epilogue: dist = esq - 2*cross, per-row argmin over this block's 128 cols.
    // C/D layout: col = lane&15, row = quad*4 + reg  (m89-verified, dtype-indep)
    #pragma unroll
    for (int mi = 0; mi < 4; ++mi) {
        #pragma unroll
        for (int r = 0; r < 4; ++r) {
            float bv = INFINITY; int bi = 0;
            #pragma unroll
            for (int ni = 0; ni < 4; ++ni) {   // ascending col -> '<' keeps low idx
                int c = wx * 64 + ni * 16 + colg;
                float dv = esq[n0 + c] - 2.0f * acc[mi][ni][r];
                if (dv < bv) { bv = dv; bi = n0 + c; }
            }
            u64 key = ((u64)fkey(bv) << 32) | (u64)(unsigned int)bi;
            #pragma unroll
            for (int off = 1; off < 16; off <<= 1) {
                u64 o = __shfl_xor(key, off);
                if (o < key) key = o;
            }
            if (colg == 0) red[wy * 64 + mi * 16 + quad * 4 + r][wx] = key;
        }
    }
    __syncthreads();
    if (tid < 128) {
        u64 a = red[tid][0], b = red[tid][1];
        best[(size_t)(m0 + tid) * 64 + nb] = (b < a) ? b : a;
    }
}

// ---------------- fallback (round-1 fp32 path) ----------------
#define KSPLIT 16
#define LDSW 132
__global__ __launch_bounds__(256, 2) void argmin_fp32(
    const float* __restrict__ X, const float* __restrict__ E,
    const float* __restrict__ esq, u64* __restrict__ best)
{
    __shared__ __align__(16) float Xs[16][LDSW];
    __shared__ __align__(16) float Es[16][LDSW];
    __shared__ u64 red[128][16];
    const int tid = threadIdx.x;
    const int tx = tid & 15, ty = tid >> 4;
    const int rowTile = blockIdx.x / KSPLIT;
    const int split   = blockIdx.x % KSPLIT;
    const int m0 = rowTile * 128;
    const int kbase = split * (Kn / KSPLIT);
    float bestv[8]; int besti[8];
    #pragma unroll
    for (int i = 0; i < 8; ++i) { bestv[i] = INFINITY; besti[i] = 0; }
    const int ldRow = tid >> 2, ldD = (tid & 3) * 4;
    for (int kt = 0; kt < (Kn / KSPLIT) / 128; ++kt) {
        const int k0 = kbase + kt * 128;
        float acc[8][8] = {};
        for (int dc = 0; dc < Dn / 16; ++dc) {
            const int d0 = dc * 16;
            float4 xa = *(const float4*)&X[(size_t)(m0 + ldRow)      * Dn + d0 + ldD];
            float4 xb = *(const float4*)&X[(size_t)(m0 + 64 + ldRow) * Dn + d0 + ldD];
            float4 ea = *(const float4*)&E[(size_t)(k0 + ldRow)      * Dn + d0 + ldD];
            float4 eb = *(const float4*)&E[(size_t)(k0 + 64 + ldRow) * Dn + d0 + ldD];
            __syncthreads();
            Xs[ldD+0][ldRow] = xa.x; Xs[ldD+1][ldRow] = xa.y;
            Xs[ldD+2][ldRow] = xa.z; Xs[ldD+3][ldRow] = xa.w;
            Xs[ldD+0][64+ldRow] = xb.x; Xs[ldD+1][64+ldRow] = xb.y;
            Xs[ldD+2][64+ldRow] = xb.z; Xs[ldD+3][64+ldRow] = xb.w;
            Es[ldD+0][ldRow] = ea.x; Es[ldD+1][ldRow] = ea.y;
            Es[ldD+2][ldRow] = ea.z; Es[ldD+3][ldRow] = ea.w;
            Es[ldD+0][64+ldRow] = eb.x; Es[ldD+1][64+ldRow] = eb.y;
            Es[ldD+2][64+ldRow] = eb.z; Es[ldD+3][64+ldRow] = eb.w;
            __syncthreads();
            #pragma unroll
            for (int d = 0; d < 16; ++d) {
                float a8[8], b8[8];
                *(float4*)&a8[0] = *(const float4*)&Xs[d][4*ty];
                *(float4*)&a8[4] = *(const float4*)&Xs[d][64 + 4*ty];
                *(float4*)&b8[0] = *(const float4*)&Es[d][4*tx];
                *(float4*)&b8[4] = *(const float4*)&Es[d][64 + 4*tx];
                #pragma unroll
                for (int i = 0; i < 8; ++i)
                    #pragma unroll
                    for (int j = 0; j < 8; ++j) acc[i][j] += a8[i] * b8[j];
            }
        }
        #pragma unroll
        for (int j = 0; j < 8; ++j) {
            const int c = k0 + ((j < 4) ? (4*tx + j) : (64 + 4*tx + (j - 4)));
            const float eq = esq[c];
            #pragma unroll
            for (int i = 0; i < 8; ++i) {
                float dval = eq - 2.0f * acc[i][j];
                if (dval < bestv[i]) { bestv[i] = dval; besti[i] = c; }
            }
        }
    }
    #pragma unroll
    for (int i = 0; i < 8; ++i) {
        int rloc = (i < 4) ? (4*ty + i) : (64 + 4*ty + (i - 4));
        red[rloc][tx] = ((u64)fkey(bestv[i]) << 32) | (u64)(unsigned int)besti[i];
    }
    __syncthreads();
    if (tid < 128) {
        u64 m = red[tid][0];
        #pragma unroll
        for (int t = 1; t < 16; ++t) { u64 v = red[tid][t]; if (v < m) m = v; }
        best[(size_t)(m0 + tid) * KSPLIT + split] = m;
    }
}

// ---------------- kernel: reduce splits, write index + residual ----------------
__global__ __launch_bounds__(128) void finalize_kernel(
    const float* __restrict__ X, const float* __restrict__ E,
    const u64* __restrict__ best, float* __restrict__ out, int nsplits)
{
    __shared__ int sidx;
    const int b = blockIdx.x, t = threadIdx.x;
    if (t < 64) {
        u64 v = (t < nsplits) ? best[(size_t)b * nsplits + t] : ~0ull;
        #pragma unroll
        for (int off = 1; off < 64; off <<= 1) {
            u64 o = __shfl_xor(v, off);
            if (o < v) v = o;
        }
        if (t == 0) {
            int idx = (int)(unsigned int)(v & 0xFFFFFFFFull);
            sidx = idx;
            out[b] = (float)idx;
        }
    }
    __syncthreads();
    const int idx = sidx;
    float4 x = ((const float4*)(X + (size_t)b * Dn))[t];
    float4 e = ((const float4*)(E + (size_t)idx * Dn))[t];
    float4 r; r.x = x.x - e.x; r.y = x.y - e.y; r.z = x.z - e.z; r.w = x.w - e.w;
    ((float4*)(out + Bn + (size_t)b * Dn))[t] = r;
}

extern "C" void kernel_launch(void* const* d_in, const int* in_sizes, int n_in,
                              void* d_out, int out_size, void* d_ws, size_t ws_size,
                              hipStream_t stream) {
    const float* X = (const float*)d_in[0];   // previous_residual [B, D]
    const float* E = (const float*)d_in[1];   // codebook_embeddings [K, D]
    float* out = (float*)d_out;               // [B] idx-as-float ++ [B*D] residual

    // fast-path ws layout: esq (32KB) | Xh | Xl | Eh | El (8MB each) | best (4MB)
    const size_t HB = (size_t)Bn * Dn * sizeof(_Float16);   // 8 MB
    const size_t NEED = 32768 + 4 * HB + (size_t)Bn * 64 * sizeof(u64);

    float* esq = (float*)d_ws;
    esq_kernel<<<Kn / 4, 256, 0, stream>>>(E, esq);

    if (ws_size >= NEED) {
        _Float16* Xh = (_Float16*)((char*)d_ws + 32768);
        _Float16* Xl = (_Float16*)((char*)d_ws + 32768 + HB);
        _Float16* Eh = (_Float16*)((char*)d_ws + 32768 + 2 * HB);
        _Float16* El = (_Float16*)((char*)d_ws + 32768 + 3 * HB);
        u64* best    = (u64*)((char*)d_ws + 32768 + 4 * HB);
        convert_kernel<<<8192, 256, 0, stream>>>(X, E, Xh, Xl, Eh, El);
        argmin_mfma<<<64 * 64, 256, 0, stream>>>(Xh, Xl, Eh, El, esq, best);
        finalize_kernel<<<Bn, 128, 0, stream>>>(X, E, best, out, 64);
    } else {
        u64* best = (u64*)((char*)d_ws + 32768);
        argmin_fp32<<<(Bn / 128) * KSPLIT, 256, 0, stream>>>(X, E, esq, best);
        finalize_kernel<<<Bn, 128, 0, stream>>>(X, E, best, out, KSPLIT);
    }
}